// Round 9
// baseline (159.255 us; speedup 1.0000x reference)
//
#include <hip/hip_runtime.h>

#define Bn 8
#define Cc 64
#define CO 64
#define Hh 128
#define Ww 128
#define Kk 9
#define HW (Hh*Ww)

typedef __attribute__((ext_vector_type(8))) short bf16x8;
typedef __attribute__((ext_vector_type(4))) float f32x4;

__device__ __forceinline__ short f2bf(float f) {
    unsigned u = __float_as_uint(f);
    u = (u + 0x7FFFu + ((u >> 16) & 1u)) >> 16;   // RNE
    return (short)u;
}

// XCD-aware swizzle: 2048 blocks, 8 XCDs, 256-block chunks (bijective: 2048%8==0)
__device__ __forceinline__ int xcd_swizzle(int bid) {
    return ((bid & 7) << 8) | (bid >> 3);
}

// ---------------- kernel 1: input NCHW fp32 -> NHWC bf16 ----------------
__global__ __launch_bounds__(256) void transpose_in_kernel(
    const float* __restrict__ in, short* __restrict__ in_t)
{
    __shared__ float tile[64 * 65];
    int bid  = xcd_swizzle(blockIdx.x);
    int xblk = bid & 1;
    int row  = bid >> 1;            // b*H + y
    int y    = row & (Hh - 1);
    int b    = row >> 7;
    int x0   = xblk << 6;
    int t    = threadIdx.x;

    int x  = t & 63;
    int cq = t >> 6;
    const float* src = in + (size_t)b * Cc * HW + (size_t)y * Ww + x0;
#pragma unroll
    for (int i = 0; i < 16; ++i) {
        int c = cq * 16 + i;
        tile[c * 65 + x] = src[(size_t)c * HW + x];
    }
    __syncthreads();
    int c2 = t & 63;
    int xq = t >> 6;
    short* dst = in_t + ((size_t)(b * Hh + y) * Ww + x0) * Cc;
#pragma unroll
    for (int i = 0; i < 16; ++i) {
        int xx = xq * 16 + i;
        dst[(size_t)xx * Cc + c2] = f2bf(tile[c2 * 65 + xx]);
    }
}

// ---------------- kernel 2: weight fp32 [co][c][k] -> bf16 [k][co][c] ----------------
__global__ __launch_bounds__(256) void prep_w_kernel(
    const float* __restrict__ w, short* __restrict__ w_t)
{
    int idx = blockIdx.x * 256 + threadIdx.x;
    if (idx < Kk * CO * Cc) {
        int k  = idx >> 12;
        int co = (idx >> 6) & 63;
        int c  = idx & 63;
        w_t[idx] = f2bf(w[((size_t)co * Cc + c) * Kk + k]);
    }
}

// ---------------- kernel 3: corner-GEMM MFMA, 2-deep gather pipeline ----------------
// Raw bf16 corner gathers feed MFMA B directly; bilinear blend in f32 D-space.
// Named double-buffered fragments (rA*/rB*): gathers for k+2 issue during body k,
// a full compute-body (~32 MFMA + STAGE VALU) ahead of consumption.
// No LDS, no barriers; all state named (no runtime-indexed arrays -> no scratch).
__global__ __launch_bounds__(256, 3) void dcn_main_kernel(
    const short* __restrict__ in_t,   // [B][H][W][C] bf16
    const float* __restrict__ offm,   // [B][27][H][W] fp32
    const short* __restrict__ w_t,    // [K][CO][C] bf16
    const float* __restrict__ bias,   // [CO] fp32
    float* __restrict__ out)          // [B][CO][H][W] fp32
{
    int bid  = xcd_swizzle(blockIdx.x);
    int xblk = bid & 1;
    int row  = bid >> 1;
    int y    = row & (Hh - 1);
    int b    = row >> 7;
    int x0   = xblk << 6;
    int t    = threadIdx.x;
    int l    = t & 63;
    int wv   = t >> 6;                // wave 0..3
    int lm   = l & 15;                // px within stripe == MFMA col
    int g    = l >> 4;                // channel group == MFMA k-chunk
    int px   = (wv << 4) + lm;

    const float* offb = offm + (size_t)b * 27 * HW + (size_t)y * Ww + x0 + px;
    const short* inb  = in_t + (size_t)b * HW * Cc;

    // preload all 27 offset scalars (constant-indexed after unroll -> registers)
    float offv[Kk][3];
#pragma unroll
    for (int k = 0; k < Kk; ++k) {
        offv[k][0] = offb[(size_t)(2 * k) * HW];
        offv[k][1] = offb[(size_t)(2 * k + 1) * HW];
        offv[k][2] = offb[(size_t)(18 + k) * HW];
    }

    f32x4 accA = {0.f,0.f,0.f,0.f};
    f32x4 accB = {0.f,0.f,0.f,0.f};
    f32x4 accC = {0.f,0.f,0.f,0.f};
    f32x4 accD = {0.f,0.f,0.f,0.f};

    // named double-buffered corner fragments + weights — NO arrays
    bf16x8 rA0a, rA0b, rA1a, rA1b, rA2a, rA2b, rA3a, rA3b;
    bf16x8 rB0a, rB0b, rB1a, rB1b, rB2a, rB2b, rB3a, rB3b;
    float  cwA0, cwA1, cwA2, cwA3;
    float  cwB0, cwB1, cwB2, cwB3;

#define STAGE(S, K) do {                                                        \
        float m_  = __builtin_amdgcn_rcpf(1.0f + __expf(-offv[K][2]));          \
        float ys_ = (float)(y + ((K) / 3) - 1) + offv[K][0];                    \
        float xs_ = (float)(x0 + px + ((K) % 3) - 1) + offv[K][1];              \
        float yf_ = floorf(ys_), xf_ = floorf(xs_);                             \
        int y0_ = (int)yf_, x0_ = (int)xf_;                                     \
        float wy_ = ys_ - yf_, wx_ = xs_ - xf_;                                 \
        bool vy0_ = (unsigned)y0_ < (unsigned)Hh;                               \
        bool vy1_ = (unsigned)(y0_ + 1) < (unsigned)Hh;                         \
        bool vx0_ = (unsigned)x0_ < (unsigned)Ww;                               \
        bool vx1_ = (unsigned)(x0_ + 1) < (unsigned)Ww;                         \
        int cy0_ = min(max(y0_, 0), Hh - 1);                                    \
        int cy1_ = min(max(y0_ + 1, 0), Hh - 1);                                \
        int cx0_ = min(max(x0_, 0), Ww - 1);                                    \
        int cx1_ = min(max(x0_ + 1, 0), Ww - 1);                                \
        cw##S##0 = (vy0_ && vx0_) ? (1.0f - wy_) * (1.0f - wx_) * m_ : 0.0f;    \
        cw##S##1 = (vy0_ && vx1_) ? (1.0f - wy_) * wx_ * m_ : 0.0f;             \
        cw##S##2 = (vy1_ && vx0_) ? wy_ * (1.0f - wx_) * m_ : 0.0f;             \
        cw##S##3 = (vy1_ && vx1_) ? wy_ * wx_ * m_ : 0.0f;                      \
        const short* p0_ = inb + (size_t)(cy0_ * Ww + cx0_) * Cc + (g << 3);    \
        const short* p1_ = inb + (size_t)(cy0_ * Ww + cx1_) * Cc + (g << 3);    \
        const short* p2_ = inb + (size_t)(cy1_ * Ww + cx0_) * Cc + (g << 3);    \
        const short* p3_ = inb + (size_t)(cy1_ * Ww + cx1_) * Cc + (g << 3);    \
        r##S##0a = *(const bf16x8*)p0_;  r##S##0b = *(const bf16x8*)(p0_ + 32); \
        r##S##1a = *(const bf16x8*)p1_;  r##S##1b = *(const bf16x8*)(p1_ + 32); \
        r##S##2a = *(const bf16x8*)p2_;  r##S##2b = *(const bf16x8*)(p2_ + 32); \
        r##S##3a = *(const bf16x8*)p3_;  r##S##3b = *(const bf16x8*)(p3_ + 32); \
    } while (0)

#define CORNER(A0, A1, RA, RB, CWT, ACC) do {                                   \
        f32x4 t_ = __builtin_amdgcn_mfma_f32_16x16x32_bf16(                     \
            (A0), (RA), (f32x4){0.f,0.f,0.f,0.f}, 0, 0, 0);                     \
        t_ = __builtin_amdgcn_mfma_f32_16x16x32_bf16((A1), (RB), t_, 0, 0, 0);  \
        (ACC)[0] = fmaf((CWT), t_[0], (ACC)[0]);                                \
        (ACC)[1] = fmaf((CWT), t_[1], (ACC)[1]);                                \
        (ACC)[2] = fmaf((CWT), t_[2], (ACC)[2]);                                \
        (ACC)[3] = fmaf((CWT), t_[3], (ACC)[3]);                                \
    } while (0)

#define DO_F(WK, F, S, ACC) do {                                                \
        bf16x8 A0_ = *(const bf16x8*)((WK) + (F) * 1024);                       \
        bf16x8 A1_ = *(const bf16x8*)((WK) + (F) * 1024 + 32);                  \
        CORNER(A0_, A1_, r##S##0a, r##S##0b, cw##S##0, ACC);                    \
        CORNER(A0_, A1_, r##S##1a, r##S##1b, cw##S##1, ACC);                    \
        CORNER(A0_, A1_, r##S##2a, r##S##2b, cw##S##2, ACC);                    \
        CORNER(A0_, A1_, r##S##3a, r##S##3b, cw##S##3, ACC);                    \
    } while (0)

#define COMPUTE(K, S) do {                                                      \
        const short* wk_ = w_t + (size_t)(K) * 4096 + lm * 64 + (g << 3);       \
        DO_F(wk_, 0, S, accA);                                                  \
        DO_F(wk_, 1, S, accB);                                                  \
        DO_F(wk_, 2, S, accC);                                                  \
        DO_F(wk_, 3, S, accD);                                                  \
    } while (0)

    // 2-deep pipelined schedule (gathers issue one full body ahead of use)
    STAGE(A, 0);
    STAGE(B, 1);
    COMPUTE(0, A); STAGE(A, 2);
    COMPUTE(1, B); STAGE(B, 3);
    COMPUTE(2, A); STAGE(A, 4);
    COMPUTE(3, B); STAGE(B, 5);
    COMPUTE(4, A); STAGE(A, 6);
    COMPUTE(5, B); STAGE(B, 7);
    COMPUTE(6, A); STAGE(A, 8);
    COMPUTE(7, B);
    COMPUTE(8, A);

#undef COMPUTE
#undef DO_F
#undef CORNER
#undef STAGE

    // epilogue: lane l holds D[co = 16F + 4g + rr][px = 16wv + lm]
    float* outb = out + (size_t)b * CO * HW + (size_t)y * Ww + x0 + (wv << 4) + lm;
#define WR_F(F, ACC) do {                                                       \
        _Pragma("unroll")                                                       \
        for (int rr = 0; rr < 4; ++rr) {                                        \
            int co = ((F) << 4) + (g << 2) + rr;                                \
            outb[(size_t)co * HW] = (ACC)[rr] + bias[co];                       \
        }                                                                       \
    } while (0)
    WR_F(0, accA);
    WR_F(1, accB);
    WR_F(2, accC);
    WR_F(3, accD);
#undef WR_F
}

// ---------------- launcher ----------------
extern "C" void kernel_launch(void* const* d_in, const int* in_sizes, int n_in,
                              void* d_out, int out_size, void* d_ws, size_t ws_size,
                              hipStream_t stream)
{
    const float* in   = (const float*)d_in[0];
    const float* offm = (const float*)d_in[1];
    const float* w    = (const float*)d_in[2];
    const float* bias = (const float*)d_in[3];
    float* out = (float*)d_out;

    short* in_t = (short*)d_ws;                          // 8*128*128*64 bf16 = 16 MiB
    short* w_t  = in_t + (size_t)Bn * HW * Cc;           // 9*64*64 bf16 = 72 KiB

    transpose_in_kernel<<<Bn * Hh * 2, 256, 0, stream>>>(in, in_t);
    prep_w_kernel<<<(Kk * CO * Cc + 255) / 256, 256, 0, stream>>>(w, w_t);
    dcn_main_kernel<<<Bn * Hh * 2, 256, 0, stream>>>(in_t, offm, w_t, bias, out);
}

// Round 10
// 86.147 us; speedup vs baseline: 1.8487x; 1.8487x over previous
//
#include <hip/hip_runtime.h>

#define Bn 8
#define Cc 64
#define CO 64
#define Hh 128
#define Ww 128
#define Kk 9
#define HW (Hh*Ww)

typedef __attribute__((ext_vector_type(8))) short bf16x8;
typedef __attribute__((ext_vector_type(4))) float f32x4;

__device__ __forceinline__ short f2bf(float f) {
    unsigned u = __float_as_uint(f);
    u = (u + 0x7FFFu + ((u >> 16) & 1u)) >> 16;   // RNE
    return (short)u;
}

// XCD-aware swizzle: 2048 blocks, 8 XCDs, 256-block chunks (bijective: 2048%8==0)
__device__ __forceinline__ int xcd_swizzle(int bid) {
    return ((bid & 7) << 8) | (bid >> 3);
}

// ---------------- kernel 1: input NCHW fp32 -> NHWC bf16 ----------------
__global__ __launch_bounds__(256) void transpose_in_kernel(
    const float* __restrict__ in, short* __restrict__ in_t)
{
    __shared__ float tile[64 * 65];
    int bid  = xcd_swizzle(blockIdx.x);
    int xblk = bid & 1;
    int row  = bid >> 1;            // b*H + y
    int y    = row & (Hh - 1);
    int b    = row >> 7;
    int x0   = xblk << 6;
    int t    = threadIdx.x;

    int x  = t & 63;
    int cq = t >> 6;
    const float* src = in + (size_t)b * Cc * HW + (size_t)y * Ww + x0;
#pragma unroll
    for (int i = 0; i < 16; ++i) {
        int c = cq * 16 + i;
        tile[c * 65 + x] = src[(size_t)c * HW + x];
    }
    __syncthreads();
    int c2 = t & 63;
    int xq = t >> 6;
    short* dst = in_t + ((size_t)(b * Hh + y) * Ww + x0) * Cc;
#pragma unroll
    for (int i = 0; i < 16; ++i) {
        int xx = xq * 16 + i;
        dst[(size_t)xx * Cc + c2] = f2bf(tile[c2 * 65 + xx]);
    }
}

// ---------------- kernel 2: weight fp32 [co][c][k] -> bf16 [k][co][c] ----------------
__global__ __launch_bounds__(256) void prep_w_kernel(
    const float* __restrict__ w, short* __restrict__ w_t)
{
    int idx = blockIdx.x * 256 + threadIdx.x;
    if (idx < Kk * CO * Cc) {
        int k  = idx >> 12;
        int co = (idx >> 6) & 63;
        int c  = idx & 63;
        w_t[idx] = f2bf(w[((size_t)co * Cc + c) * Kk + k]);
    }
}

// ---------------- kernel 3: corner-GEMM MFMA + LDS-W pipeline ----------------
// A-operand (weights) from LDS (lgkmcnt) -> decoupled from gather vmcnt, so
// gathers for k+1 stay in flight across COMPUTE(k). Corner fragments live in
// named double-buffered registers; bilinear blend in f32 D-space.
__global__ __launch_bounds__(256, 3) void dcn_main_kernel(
    const short* __restrict__ in_t,   // [B][H][W][C] bf16
    const float* __restrict__ offm,   // [B][27][H][W] fp32
    const short* __restrict__ w_t,    // [K][CO][C] bf16
    const float* __restrict__ bias,   // [CO] fp32
    float* __restrict__ out)          // [B][CO][H][W] fp32
{
    __shared__ short s_W[2][64][72];  // weight bf16 [co][c], pad 72 (even banks)

    int bid  = xcd_swizzle(blockIdx.x);
    int xblk = bid & 1;
    int row  = bid >> 1;
    int y    = row & (Hh - 1);
    int b    = row >> 7;
    int x0   = xblk << 6;
    int t    = threadIdx.x;
    int l    = t & 63;
    int wv   = t >> 6;                // wave 0..3
    int lm   = l & 15;                // px within stripe == MFMA col
    int g    = l >> 4;                // channel group == MFMA k-chunk
    int px   = (wv << 4) + lm;

    const float* offb = offm + (size_t)b * 27 * HW + (size_t)y * Ww + x0 + px;
    const short* inb  = in_t + (size_t)b * HW * Cc;

    int wco = t >> 2;                 // W staging: 256 threads cover 64co x 64c
    int wc0 = (t & 3) << 4;

    // preload all 27 offset scalars (literal-indexed after expansion -> registers)
    float offv[Kk][3];
#pragma unroll
    for (int k = 0; k < Kk; ++k) {
        offv[k][0] = offb[(size_t)(2 * k) * HW];
        offv[k][1] = offb[(size_t)(2 * k + 1) * HW];
        offv[k][2] = offb[(size_t)(18 + k) * HW];
    }

    f32x4 accA = {0.f,0.f,0.f,0.f};
    f32x4 accB = {0.f,0.f,0.f,0.f};
    f32x4 accC = {0.f,0.f,0.f,0.f};
    f32x4 accD = {0.f,0.f,0.f,0.f};

    // named double-buffered corner fragments + weights — NO arrays (rule #20)
    bf16x8 rA0a, rA0b, rA1a, rA1b, rA2a, rA2b, rA3a, rA3b;
    bf16x8 rB0a, rB0b, rB1a, rB1b, rB2a, rB2b, rB3a, rB3b;
    float  cwA0, cwA1, cwA2, cwA3;
    float  cwB0, cwB1, cwB2, cwB3;
    uint4  wq0, wq1;                  // in-flight W slice

#define W_LOAD(K) do {                                                          \
        const uint4* wk_ = (const uint4*)(w_t + (size_t)(K) * 4096 + 16 * t);   \
        wq0 = wk_[0];                                                           \
        wq1 = wk_[1];                                                           \
    } while (0)

#define W_STORE(NB) do {                                                        \
        *(uint4*)&s_W[NB][wco][wc0]     = wq0;                                  \
        *(uint4*)&s_W[NB][wco][wc0 + 8] = wq1;                                  \
    } while (0)

#define STAGE(S, K) do {                                                        \
        float m_  = __builtin_amdgcn_rcpf(1.0f + __expf(-offv[K][2]));          \
        float ys_ = (float)(y + ((K) / 3) - 1) + offv[K][0];                    \
        float xs_ = (float)(x0 + px + ((K) % 3) - 1) + offv[K][1];              \
        float yf_ = floorf(ys_), xf_ = floorf(xs_);                             \
        int y0_ = (int)yf_, x0_ = (int)xf_;                                     \
        float wy_ = ys_ - yf_, wx_ = xs_ - xf_;                                 \
        bool vy0_ = (unsigned)y0_ < (unsigned)Hh;                               \
        bool vy1_ = (unsigned)(y0_ + 1) < (unsigned)Hh;                         \
        bool vx0_ = (unsigned)x0_ < (unsigned)Ww;                               \
        bool vx1_ = (unsigned)(x0_ + 1) < (unsigned)Ww;                         \
        int cy0_ = min(max(y0_, 0), Hh - 1);                                    \
        int cy1_ = min(max(y0_ + 1, 0), Hh - 1);                                \
        int cx0_ = min(max(x0_, 0), Ww - 1);                                    \
        int cx1_ = min(max(x0_ + 1, 0), Ww - 1);                                \
        cw##S##0 = (vy0_ && vx0_) ? (1.0f - wy_) * (1.0f - wx_) * m_ : 0.0f;    \
        cw##S##1 = (vy0_ && vx1_) ? (1.0f - wy_) * wx_ * m_ : 0.0f;             \
        cw##S##2 = (vy1_ && vx0_) ? wy_ * (1.0f - wx_) * m_ : 0.0f;             \
        cw##S##3 = (vy1_ && vx1_) ? wy_ * wx_ * m_ : 0.0f;                      \
        const short* p0_ = inb + (size_t)(cy0_ * Ww + cx0_) * Cc + (g << 3);    \
        const short* p1_ = inb + (size_t)(cy0_ * Ww + cx1_) * Cc + (g << 3);    \
        const short* p2_ = inb + (size_t)(cy1_ * Ww + cx0_) * Cc + (g << 3);    \
        const short* p3_ = inb + (size_t)(cy1_ * Ww + cx1_) * Cc + (g << 3);    \
        r##S##0a = *(const bf16x8*)p0_;  r##S##0b = *(const bf16x8*)(p0_ + 32); \
        r##S##1a = *(const bf16x8*)p1_;  r##S##1b = *(const bf16x8*)(p1_ + 32); \
        r##S##2a = *(const bf16x8*)p2_;  r##S##2b = *(const bf16x8*)(p2_ + 32); \
        r##S##3a = *(const bf16x8*)p3_;  r##S##3b = *(const bf16x8*)(p3_ + 32); \
    } while (0)

#define CORNER(A0, A1, RA, RB, CWT, ACC) do {                                   \
        f32x4 t_ = __builtin_amdgcn_mfma_f32_16x16x32_bf16(                     \
            (A0), (RA), (f32x4){0.f,0.f,0.f,0.f}, 0, 0, 0);                     \
        t_ = __builtin_amdgcn_mfma_f32_16x16x32_bf16((A1), (RB), t_, 0, 0, 0);  \
        (ACC)[0] = fmaf((CWT), t_[0], (ACC)[0]);                                \
        (ACC)[1] = fmaf((CWT), t_[1], (ACC)[1]);                                \
        (ACC)[2] = fmaf((CWT), t_[2], (ACC)[2]);                                \
        (ACC)[3] = fmaf((CWT), t_[3], (ACC)[3]);                                \
    } while (0)

#define DO_F(CB, F, S, ACC) do {                                                \
        bf16x8 A0_ = *(const bf16x8*)&s_W[CB][((F) << 4) + lm][(g << 3)];       \
        bf16x8 A1_ = *(const bf16x8*)&s_W[CB][((F) << 4) + lm][32 + (g << 3)];  \
        CORNER(A0_, A1_, r##S##0a, r##S##0b, cw##S##0, ACC);                    \
        CORNER(A0_, A1_, r##S##1a, r##S##1b, cw##S##1, ACC);                    \
        CORNER(A0_, A1_, r##S##2a, r##S##2b, cw##S##2, ACC);                    \
        CORNER(A0_, A1_, r##S##3a, r##S##3b, cw##S##3, ACC);                    \
    } while (0)

#define COMPUTE(CB, S) do {                                                     \
        DO_F(CB, 0, S, accA);                                                   \
        DO_F(CB, 1, S, accB);                                                   \
        DO_F(CB, 2, S, accC);                                                   \
        DO_F(CB, 3, S, accD);                                                   \
    } while (0)

    // body k: w_load(k+1) FIRST (so consuming wq waits at vmcnt<=8, gathers
    // stay in flight) -> STAGE(k+1) gathers -> COMPUTE(k) (ds_read A: lgkmcnt,
    // r(k): vmcnt<=10) -> w_store(k+1) -> barrier.
    W_LOAD(0); STAGE(A, 0); W_STORE(0);
    __syncthreads();

    W_LOAD(1); STAGE(B, 1); COMPUTE(0, A); W_STORE(1); __syncthreads();
    W_LOAD(2); STAGE(A, 2); COMPUTE(1, B); W_STORE(0); __syncthreads();
    W_LOAD(3); STAGE(B, 3); COMPUTE(0, A); W_STORE(1); __syncthreads();
    W_LOAD(4); STAGE(A, 4); COMPUTE(1, B); W_STORE(0); __syncthreads();
    W_LOAD(5); STAGE(B, 5); COMPUTE(0, A); W_STORE(1); __syncthreads();
    W_LOAD(6); STAGE(A, 6); COMPUTE(1, B); W_STORE(0); __syncthreads();
    W_LOAD(7); STAGE(B, 7); COMPUTE(0, A); W_STORE(1); __syncthreads();
    W_LOAD(8); STAGE(A, 8); COMPUTE(1, B); W_STORE(0); __syncthreads();
    COMPUTE(0, A);

#undef COMPUTE
#undef DO_F
#undef CORNER
#undef STAGE
#undef W_STORE
#undef W_LOAD

    // epilogue: lane l holds D[co = 16F + 4g + rr][px = 16wv + lm]
    float* outb = out + (size_t)b * CO * HW + (size_t)y * Ww + x0 + (wv << 4) + lm;
#define WR_F(F, ACC) do {                                                       \
        _Pragma("unroll")                                                       \
        for (int rr = 0; rr < 4; ++rr) {                                        \
            int co = ((F) << 4) + (g << 2) + rr;                                \
            outb[(size_t)co * HW] = (ACC)[rr] + bias[co];                       \
        }                                                                       \
    } while (0)
    WR_F(0, accA);
    WR_F(1, accB);
    WR_F(2, accC);
    WR_F(3, accD);
#undef WR_F
}

// ---------------- launcher ----------------
extern "C" void kernel_launch(void* const* d_in, const int* in_sizes, int n_in,
                              void* d_out, int out_size, void* d_ws, size_t ws_size,
                              hipStream_t stream)
{
    const float* in   = (const float*)d_in[0];
    const float* offm = (const float*)d_in[1];
    const float* w    = (const float*)d_in[2];
    const float* bias = (const float*)d_in[3];
    float* out = (float*)d_out;

    short* in_t = (short*)d_ws;                          // 8*128*128*64 bf16 = 16 MiB
    short* w_t  = in_t + (size_t)Bn * HW * Cc;           // 9*64*64 bf16 = 72 KiB

    transpose_in_kernel<<<Bn * Hh * 2, 256, 0, stream>>>(in, in_t);
    prep_w_kernel<<<(Kk * CO * Cc + 255) / 256, 256, 0, stream>>>(w, w_t);
    dcn_main_kernel<<<Bn * Hh * 2, 256, 0, stream>>>(in_t, offm, w_t, bias, out);
}